// Round 1
// baseline (119.095 us; speedup 1.0000x reference)
//
#include <hip/hip_runtime.h>

// Problem constants (from reference):
//   N_KV_HEADS=8, MAX_CONTEXT=8192, HEAD_DIM=128, N_NEW=16, dtype fp32
// Output = concat(kout, vout) flat, each (1,8,8192,128) fp32.
//
// Layout in float4 units:
//   per-cache float4 count: 8*8192*(128/4) = 8*8192*32 = 2^21
//   total output float4s  : 2^22
//   j (index within one cache):  h = j>>18,  s = (j>>5)&8191,  d4 = j&31

#define NNEW 16

__global__ __launch_bounds__(256) void kv_update_kernel(
    const int* __restrict__ pos,
    const float4* __restrict__ knew,
    const float4* __restrict__ vnew,
    const float4* __restrict__ kcache,
    const float4* __restrict__ vcache,
    float4* __restrict__ out)
{
    const unsigned int i = blockIdx.x * 256u + threadIdx.x;   // [0, 2^22)

    const unsigned int is_v = i >> 21;
    const unsigned int j = i & ((1u << 21) - 1u);
    const unsigned int h  = j >> 18;          // head, 0..7
    const int          s  = (int)((j >> 5) & 8191u);  // seq position
    const unsigned int d4 = j & 31u;          // float4 index within head_dim

    // pos is wave-uniform (constant offsets off a kernarg pointer) -> s_loads.
    // Last match wins => numpy sequential-assignment semantics for dup indices.
    int match = -1;
#pragma unroll
    for (int n = 0; n < NNEW; ++n) {
        if (pos[n] == s) match = n;
    }

    float4 val;
    if (match >= 0) {
        const float4* __restrict__ src = is_v ? vnew : knew;
        // new tensor layout: (1, 8, 16, 128) -> (h*16 + n)*32 + d4 float4s
        val = src[(h * NNEW + (unsigned)match) * 32u + d4];
    } else {
        const float4* __restrict__ src = is_v ? vcache : kcache;
        val = src[j];
    }
    out[i] = val;
}

extern "C" void kernel_launch(void* const* d_in, const int* in_sizes, int n_in,
                              void* d_out, int out_size, void* d_ws, size_t ws_size,
                              hipStream_t stream) {
    // setup_inputs order: pos_ids, k, v, k_cache, v_cache
    const int*    pos    = (const int*)   d_in[0];
    const float4* knew   = (const float4*)d_in[1];
    const float4* vnew   = (const float4*)d_in[2];
    const float4* kcache = (const float4*)d_in[3];
    const float4* vcache = (const float4*)d_in[4];
    float4*       out    = (float4*)d_out;

    // total float4 elements = 2 caches * 2^21 = 2^22 ; 256 threads/block
    const unsigned int nblocks = (1u << 22) / 256u;  // 16384
    kv_update_kernel<<<nblocks, 256, 0, stream>>>(pos, knew, vnew, kcache, vcache, out);
}